// Round 1
// baseline (1092.920 us; speedup 1.0000x reference)
//
#include <hip/hip_runtime.h>
#include <math.h>

#define NN 50000          // nodes
#define NE 800000         // edges (without self loops)
#define NT (NE + NN)      // edges incl self loops
#define MINF_MAPPED 0x007FFFFFu   // fmap(-inf)

// ---- monotone float<->uint mapping for atomicMax on floats ----
__device__ __forceinline__ unsigned fmap(float f) {
  unsigned u = __float_as_uint(f);
  return (u & 0x80000000u) ? ~u : (u | 0x80000000u);
}
__device__ __forceinline__ float funmap(unsigned u) {
  return (u & 0x80000000u) ? __uint_as_float(u & 0x7FFFFFFFu) : __uint_as_float(~u);
}

// ---------------- init ----------------
__global__ void k_init(float* acc, long long nacc, float* denom, unsigned* m, int nm) {
  long long i = (long long)blockIdx.x * blockDim.x + threadIdx.x;
  long long stride = (long long)gridDim.x * blockDim.x;
  for (long long k = i; k < nacc; k += stride) acc[k] = 0.f;
  for (long long k = i; k < nm; k += stride) { denom[k] = 0.f; m[k] = MINF_MAPPED; }
}

// ---------------- layer 1 GEMM (128->128) + alpha reduction ----------------
// block: 128 threads, 8 rows per block. W1 staged in LDS (64KB).
__global__ __launch_bounds__(128) void k_gemm1(
    const float* __restrict__ x, const float* __restrict__ W1,
    const float* __restrict__ asw_g, const float* __restrict__ adw_g,
    float* __restrict__ h1, float* __restrict__ as1, float* __restrict__ ad1) {
  __shared__ float sW[128 * 128];
  __shared__ float srow[8][128];
  const int t = threadIdx.x;
  for (int i = t; i < 128 * 128; i += 128) sW[i] = W1[i];
  const int n0 = blockIdx.x * 8;
  for (int r = 0; r < 8; ++r) {
    int n = n0 + r;
    srow[r][t] = (n < NN) ? x[(long long)n * 128 + t] : 0.f;
  }
  __syncthreads();
  const float asw = asw_g[t];  // a_src1 flat [2*64], t = head*64+c
  const float adw = adw_g[t];
  const int lane = t & 63;
  const int head = t >> 6;
  for (int r = 0; r < 8; ++r) {
    int n = n0 + r;
    if (n >= NN) break;
    float acc = 0.f;
#pragma unroll 8
    for (int k = 0; k < 128; ++k) acc += srow[r][k] * sW[k * 128 + t];
    h1[(long long)n * 128 + t] = acc;
    float vs = acc * asw, vd = acc * adw;
    for (int off = 32; off > 0; off >>= 1) {
      vs += __shfl_down(vs, off);
      vd += __shfl_down(vd, off);
    }
    if (lane == 0) { as1[n * 2 + head] = vs; ad1[n * 2 + head] = vd; }
  }
}

// ---------------- layer 1 edge passes ----------------
__global__ __launch_bounds__(256) void k_edge_max1(
    const int* __restrict__ src, const int* __restrict__ dst,
    const float* __restrict__ as1, const float* __restrict__ ad1,
    float* __restrict__ e1, unsigned* __restrict__ m1) {
  int i = blockIdx.x * 256 + threadIdx.x;
  if (i >= NT) return;
  int s, d;
  if (i < NE) { s = src[i]; d = dst[i]; } else { s = d = i - NE; }
#pragma unroll
  for (int h = 0; h < 2; ++h) {
    float e = as1[s * 2 + h] + ad1[d * 2 + h];
    e = e > 0.f ? e : 0.2f * e;
    e1[(long long)i * 2 + h] = e;
    atomicMax(&m1[d * 2 + h], fmap(e));
  }
}

__global__ __launch_bounds__(256) void k_edge_exp1(
    const int* __restrict__ dst, const float* __restrict__ m_in_e,  // e1 in place
    float* __restrict__ e1, const unsigned* __restrict__ m1, float* __restrict__ denom1) {
  int i = blockIdx.x * 256 + threadIdx.x;
  if (i >= NT) return;
  int d = (i < NE) ? dst[i] : (i - NE);
#pragma unroll
  for (int h = 0; h < 2; ++h) {
    float e = e1[(long long)i * 2 + h];
    float w = expf(e - funmap(m1[d * 2 + h]));
    e1[(long long)i * 2 + h] = w;
    atomicAdd(&denom1[d * 2 + h], w);
  }
}

// one edge per 128 threads; c = head*64 + ch
__global__ __launch_bounds__(256) void k_agg1(
    const int* __restrict__ src, const int* __restrict__ dst,
    const float* __restrict__ w1, const float* __restrict__ h1,
    float* __restrict__ acc1) {
  long long gid = (long long)blockIdx.x * 256 + threadIdx.x;
  long long i = gid >> 7;
  int c = (int)(gid & 127);
  if (i >= NT) return;
  int s, d;
  if (i < NE) { s = src[i]; d = dst[i]; } else { s = d = (int)(i - NE); }
  float w = w1[i * 2 + (c >> 6)];
  atomicAdd(&acc1[(long long)d * 128 + c], w * h1[(long long)s * 128 + c]);
}

__global__ __launch_bounds__(256) void k_fin1(
    const float* __restrict__ acc1, const float* __restrict__ denom1,
    const float* __restrict__ b1, float* __restrict__ out1) {
  int gid = blockIdx.x * 256 + threadIdx.x;
  int n = gid >> 6, c = gid & 63;
  if (n >= NN) return;
  float v0 = acc1[(long long)n * 128 + c] / (denom1[n * 2] + 1e-16f);
  float v1 = acc1[(long long)n * 128 + 64 + c] / (denom1[n * 2 + 1] + 1e-16f);
  float v = 0.5f * (v0 + v1) + b1[c];
  out1[(long long)n * 64 + c] = v > 0.f ? v : expm1f(v);
}

// ---------------- layer 2 GEMM (64->64) + alpha ----------------
__global__ __launch_bounds__(64) void k_gemm2(
    const float* __restrict__ in, const float* __restrict__ W2,
    const float* __restrict__ asw_g, const float* __restrict__ adw_g,
    float* __restrict__ h2, float* __restrict__ as2, float* __restrict__ ad2) {
  __shared__ float sW[64 * 64];
  __shared__ float srow[16][64];
  const int t = threadIdx.x;
  for (int i = t; i < 64 * 64; i += 64) sW[i] = W2[i];
  const int n0 = blockIdx.x * 16;
  for (int r = 0; r < 16; ++r) {
    int n = n0 + r;
    srow[r][t] = (n < NN) ? in[(long long)n * 64 + t] : 0.f;
  }
  __syncthreads();
  const float asw = asw_g[t], adw = adw_g[t];
  for (int r = 0; r < 16; ++r) {
    int n = n0 + r;
    if (n >= NN) break;
    float acc = 0.f;
#pragma unroll 8
    for (int k = 0; k < 64; ++k) acc += srow[r][k] * sW[k * 64 + t];
    h2[(long long)n * 64 + t] = acc;
    float vs = acc * asw, vd = acc * adw;
    for (int off = 32; off > 0; off >>= 1) {
      vs += __shfl_down(vs, off);
      vd += __shfl_down(vd, off);
    }
    if (t == 0) { as2[n] = vs; ad2[n] = vd; }
  }
}

// ---------------- layer 2 edge passes (1 head) ----------------
__global__ __launch_bounds__(256) void k_edge_max2(
    const int* __restrict__ src, const int* __restrict__ dst,
    const float* __restrict__ as2, const float* __restrict__ ad2,
    float* __restrict__ e2, unsigned* __restrict__ m2) {
  int i = blockIdx.x * 256 + threadIdx.x;
  if (i >= NT) return;
  int s, d;
  if (i < NE) { s = src[i]; d = dst[i]; } else { s = d = i - NE; }
  float e = as2[s] + ad2[d];
  e = e > 0.f ? e : 0.2f * e;
  e2[i] = e;
  atomicMax(&m2[d], fmap(e));
}

__global__ __launch_bounds__(256) void k_edge_exp2(
    const int* __restrict__ dst, float* __restrict__ e2,
    const unsigned* __restrict__ m2, float* __restrict__ denom2) {
  int i = blockIdx.x * 256 + threadIdx.x;
  if (i >= NT) return;
  int d = (i < NE) ? dst[i] : (i - NE);
  float w = expf(e2[i] - funmap(m2[d]));
  e2[i] = w;
  atomicAdd(&denom2[d], w);
}

__global__ __launch_bounds__(256) void k_agg2(
    const int* __restrict__ src, const int* __restrict__ dst,
    const float* __restrict__ w2, const float* __restrict__ h2,
    float* __restrict__ acc2) {
  long long gid = (long long)blockIdx.x * 256 + threadIdx.x;
  long long i = gid >> 6;
  int c = (int)(gid & 63);
  if (i >= NT) return;
  int s, d;
  if (i < NE) { s = src[i]; d = dst[i]; } else { s = d = (int)(i - NE); }
  atomicAdd(&acc2[(long long)d * 64 + c], w2[i] * h2[(long long)s * 64 + c]);
}

// ---------------- finalize: ELU + classifier + log_softmax ----------------
__global__ __launch_bounds__(256) void k_fin2(
    const float* __restrict__ acc2, const float* __restrict__ denom2,
    const float* __restrict__ b2, const float* __restrict__ Wc,
    const float* __restrict__ bc, float* __restrict__ out) {
  int gid = blockIdx.x * 256 + threadIdx.x;
  int n = gid >> 6, c = gid & 63;
  if (n >= NN) return;
  float v = acc2[(long long)n * 64 + c] / (denom2[n] + 1e-16f) + b2[c];
  v = v > 0.f ? v : expm1f(v);
  float l0 = v * Wc[c * 2], l1 = v * Wc[c * 2 + 1];
  for (int off = 32; off > 0; off >>= 1) {
    l0 += __shfl_down(l0, off);
    l1 += __shfl_down(l1, off);
  }
  if (c == 0) {
    l0 += bc[0]; l1 += bc[1];
    float mx = fmaxf(l0, l1);
    float lse = mx + logf(expf(l0 - mx) + expf(l1 - mx));
    out[n * 2] = l0 - lse;
    out[n * 2 + 1] = l1 - lse;
  }
}

extern "C" void kernel_launch(void* const* d_in, const int* in_sizes, int n_in,
                              void* d_out, int out_size, void* d_ws, size_t ws_size,
                              hipStream_t stream) {
  const float* x    = (const float*)d_in[0];
  const int*   ei   = (const int*)d_in[1];     // [2,E] int32 (harness narrows int64)
  const float* W1   = (const float*)d_in[2];
  const float* as1w = (const float*)d_in[3];
  const float* ad1w = (const float*)d_in[4];
  const float* b1   = (const float*)d_in[5];
  const float* W2   = (const float*)d_in[6];
  const float* as2w = (const float*)d_in[7];
  const float* ad2w = (const float*)d_in[8];
  const float* b2   = (const float*)d_in[9];
  const float* Wc   = (const float*)d_in[10];
  const float* bc   = (const float*)d_in[11];
  float* out = (float*)d_out;

  const int* src = ei;
  const int* dst = ei + NE;

  // ---- workspace layout (floats), with layer-2 aliasing ----
  float* p = (float*)d_ws;
  float* h1    = p; p += (long long)NN * 128;   // layer2: out1 aliases h1
  float* acc1  = p; p += (long long)NN * 128;   // layer2: h2 = acc1[0:N*64], acc2 = acc1[N*64:]
  float* as1   = p; p += NN * 2;
  float* ad1   = p; p += NN * 2;
  float* den1  = p; p += NN * 2;
  unsigned* m1 = (unsigned*)p; p += NN * 2;
  float* w1e   = p; p += (long long)NT * 2;     // layer2: w2e aliases w1e

  float* out1 = h1;
  float* h2   = acc1;
  float* acc2 = acc1 + (long long)NN * 64;
  float* as2 = as1; float* ad2 = ad1; float* den2 = den1;
  unsigned* m2 = m1;
  float* w2e = w1e;

  // ---- layer 1 ----
  k_init<<<2048, 256, 0, stream>>>(acc1, (long long)NN * 128, den1, m1, NN * 2);
  k_gemm1<<<(NN + 7) / 8, 128, 0, stream>>>(x, W1, as1w, ad1w, h1, as1, ad1);
  k_edge_max1<<<(NT + 255) / 256, 256, 0, stream>>>(src, dst, as1, ad1, w1e, m1);
  k_edge_exp1<<<(NT + 255) / 256, 256, 0, stream>>>(dst, w1e, w1e, m1, den1);
  k_agg1<<<(int)(((long long)NT * 128 + 255) / 256), 256, 0, stream>>>(src, dst, w1e, h1, acc1);
  k_fin1<<<(NN * 64 + 255) / 256, 256, 0, stream>>>(acc1, den1, b1, out1);

  // ---- layer 2 ----
  k_init<<<2048, 256, 0, stream>>>(acc2, (long long)NN * 64, den2, m2, NN);
  k_gemm2<<<(NN + 15) / 16, 64, 0, stream>>>(out1, W2, as2w, ad2w, h2, as2, ad2);
  k_edge_max2<<<(NT + 255) / 256, 256, 0, stream>>>(src, dst, as2, ad2, w2e, m2);
  k_edge_exp2<<<(NT + 255) / 256, 256, 0, stream>>>(dst, w2e, m2, den2);
  k_agg2<<<(int)(((long long)NT * 64 + 255) / 256), 256, 0, stream>>>(src, dst, w2e, h2, acc2);
  k_fin2<<<(NN * 64 + 255) / 256, 256, 0, stream>>>(acc2, den2, b2, Wc, bc, out);
}

// Round 2
// 555.231 us; speedup vs baseline: 1.9684x; 1.9684x over previous
//
#include <hip/hip_runtime.h>
#include <math.h>

#define NN 50000          // nodes
#define NE 800000         // edges (without self loops)
#define NT (NE + NN)      // edges incl self loops
#define SCAN_BLK 1024
#define NSCAN ((NN + SCAN_BLK - 1) / SCAN_BLK)   // 49

// ================= CSR build =================
__global__ __launch_bounds__(256) void k_csr_zero(int* deg, int* cursor) {
  int i = blockIdx.x * 256 + threadIdx.x;
  if (i < NN) { deg[i] = 0; cursor[i] = 0; }
}

__global__ __launch_bounds__(256) void k_csr_count(const int* __restrict__ dst, int* __restrict__ deg) {
  int i = blockIdx.x * 256 + threadIdx.x;
  if (i >= NT) return;
  int d = (i < NE) ? dst[i] : (i - NE);
  atomicAdd(&deg[d], 1);
}

__global__ __launch_bounds__(SCAN_BLK) void k_scan1(const int* __restrict__ deg,
                                                    int* __restrict__ rowptr, int* __restrict__ part) {
  __shared__ int s[SCAN_BLK];
  int t = threadIdx.x;
  int g = blockIdx.x * SCAN_BLK + t;
  s[t] = (g < NN) ? deg[g] : 0;
  __syncthreads();
  for (int off = 1; off < SCAN_BLK; off <<= 1) {
    int u = (t >= off) ? s[t - off] : 0;
    __syncthreads();
    s[t] += u;
    __syncthreads();
  }
  if (g < NN) rowptr[g + 1] = s[t];
  if (t == SCAN_BLK - 1) part[blockIdx.x] = s[t];
}

__global__ void k_scan2(int* part) {
  if (threadIdx.x == 0 && blockIdx.x == 0) {
    int run = 0;
    for (int b = 0; b < NSCAN; ++b) { int v = part[b]; part[b] = run; run += v; }
  }
}

__global__ __launch_bounds__(SCAN_BLK) void k_scan3(int* __restrict__ rowptr, const int* __restrict__ part) {
  int t = threadIdx.x;
  int g = blockIdx.x * SCAN_BLK + t;
  if (g < NN) rowptr[g + 1] += part[blockIdx.x];
  if (g == 0) rowptr[0] = 0;
}

__global__ __launch_bounds__(256) void k_csr_scatter(const int* __restrict__ src, const int* __restrict__ dst,
                                                     const int* __restrict__ rowptr, int* __restrict__ cursor,
                                                     int* __restrict__ csr_src) {
  int i = blockIdx.x * 256 + threadIdx.x;
  if (i >= NT) return;
  int s, d;
  if (i < NE) { s = src[i]; d = dst[i]; } else { s = d = i - NE; }
  int pos = atomicAdd(&cursor[d], 1);
  csr_src[rowptr[d] + pos] = s;
}

// ================= layer 1 GEMM (128->128) + alpha reduction =================
__global__ __launch_bounds__(128) void k_gemm1(
    const float* __restrict__ x, const float* __restrict__ W1,
    const float* __restrict__ asw_g, const float* __restrict__ adw_g,
    float* __restrict__ h1, float* __restrict__ as1, float* __restrict__ ad1) {
  __shared__ float sW[128 * 128];
  __shared__ float srow[8][128];
  const int t = threadIdx.x;
  for (int i = t; i < 128 * 128; i += 128) sW[i] = W1[i];
  const int n0 = blockIdx.x * 8;
  for (int r = 0; r < 8; ++r) {
    int n = n0 + r;
    srow[r][t] = (n < NN) ? x[(long long)n * 128 + t] : 0.f;
  }
  __syncthreads();
  const float asw = asw_g[t];
  const float adw = adw_g[t];
  const int lane = t & 63;
  const int head = t >> 6;
  for (int r = 0; r < 8; ++r) {
    int n = n0 + r;
    if (n >= NN) break;
    float acc = 0.f;
#pragma unroll 8
    for (int k = 0; k < 128; ++k) acc += srow[r][k] * sW[k * 128 + t];
    h1[(long long)n * 128 + t] = acc;
    float vs = acc * asw, vd = acc * adw;
    for (int off = 32; off > 0; off >>= 1) {
      vs += __shfl_down(vs, off);
      vd += __shfl_down(vd, off);
    }
    if (lane == 0) { as1[n * 2 + head] = vs; ad1[n * 2 + head] = vd; }
  }
}

// ================= layer 1 fused GAT: online softmax + aggregate + mean + ELU =================
// one block (128 threads = 2 waves) per dst node; thread t = head*64 + channel
__global__ __launch_bounds__(128) void k_gat1(
    const int* __restrict__ rowptr, const int* __restrict__ csr_src,
    const float* __restrict__ h1, const float* __restrict__ as1, const float* __restrict__ ad1,
    const float* __restrict__ b1, float* __restrict__ out1) {
  const int n = blockIdx.x;
  const int t = threadIdx.x;
  const int head = t >> 6;
  const int beg = rowptr[n], end = rowptr[n + 1];
  const float ad = ad1[n * 2 + head];
  float m = -1e30f, denom = 0.f, acc = 0.f;
  for (int k = beg; k < end; ++k) {
    int s = csr_src[k];
    float e = as1[s * 2 + head] + ad;
    e = e > 0.f ? e : 0.2f * e;
    if (e > m) {
      float r = __expf(m - e);
      acc *= r; denom *= r; m = e;
    }
    float w = __expf(e - m);
    denom += w;
    acc += w * h1[s * 128 + t];
  }
  float v = acc / (denom + 1e-16f);
  __shared__ float tmp[64];
  if (t >= 64) tmp[t - 64] = v;
  __syncthreads();
  if (t < 64) {
    float u = 0.5f * (v + tmp[t]) + b1[t];
    u = u > 0.f ? u : expm1f(u);
    out1[n * 64 + t] = u;
  }
}

// ================= layer 2 GEMM (64->64) + alpha =================
__global__ __launch_bounds__(64) void k_gemm2(
    const float* __restrict__ in, const float* __restrict__ W2,
    const float* __restrict__ asw_g, const float* __restrict__ adw_g,
    float* __restrict__ h2, float* __restrict__ as2, float* __restrict__ ad2) {
  __shared__ float sW[64 * 64];
  __shared__ float srow[16][64];
  const int t = threadIdx.x;
  for (int i = t; i < 64 * 64; i += 64) sW[i] = W2[i];
  const int n0 = blockIdx.x * 16;
  for (int r = 0; r < 16; ++r) {
    int n = n0 + r;
    srow[r][t] = (n < NN) ? in[(long long)n * 64 + t] : 0.f;
  }
  __syncthreads();
  const float asw = asw_g[t], adw = adw_g[t];
  for (int r = 0; r < 16; ++r) {
    int n = n0 + r;
    if (n >= NN) break;
    float acc = 0.f;
#pragma unroll 8
    for (int k = 0; k < 64; ++k) acc += srow[r][k] * sW[k * 64 + t];
    h2[(long long)n * 64 + t] = acc;
    float vs = acc * asw, vd = acc * adw;
    for (int off = 32; off > 0; off >>= 1) {
      vs += __shfl_down(vs, off);
      vd += __shfl_down(vd, off);
    }
    if (t == 0) { as2[n] = vs; ad2[n] = vd; }
  }
}

// ================= layer 2 fused GAT + classifier + log_softmax =================
// one wave per dst node, 4 nodes per 256-thread block
__global__ __launch_bounds__(256) void k_gat2(
    const int* __restrict__ rowptr, const int* __restrict__ csr_src,
    const float* __restrict__ h2, const float* __restrict__ as2, const float* __restrict__ ad2,
    const float* __restrict__ b2, const float* __restrict__ Wc, const float* __restrict__ bc,
    float* __restrict__ out) {
  const int t = threadIdx.x;
  const int wave = t >> 6;
  const int c = t & 63;
  const int n = blockIdx.x * 4 + wave;
  if (n >= NN) return;
  const int beg = rowptr[n], end = rowptr[n + 1];
  const float ad = ad2[n];
  float m = -1e30f, denom = 0.f, acc = 0.f;
  for (int k = beg; k < end; ++k) {
    int s = csr_src[k];
    float e = as2[s] + ad;
    e = e > 0.f ? e : 0.2f * e;
    if (e > m) {
      float r = __expf(m - e);
      acc *= r; denom *= r; m = e;
    }
    float w = __expf(e - m);
    denom += w;
    acc += w * h2[s * 64 + c];
  }
  float v = acc / (denom + 1e-16f) + b2[c];
  v = v > 0.f ? v : expm1f(v);
  float l0 = v * Wc[c * 2], l1 = v * Wc[c * 2 + 1];
  for (int off = 32; off > 0; off >>= 1) {
    l0 += __shfl_down(l0, off);
    l1 += __shfl_down(l1, off);
  }
  if (c == 0) {
    l0 += bc[0]; l1 += bc[1];
    float mx = fmaxf(l0, l1);
    float lse = mx + logf(expf(l0 - mx) + expf(l1 - mx));
    out[n * 2] = l0 - lse;
    out[n * 2 + 1] = l1 - lse;
  }
}

extern "C" void kernel_launch(void* const* d_in, const int* in_sizes, int n_in,
                              void* d_out, int out_size, void* d_ws, size_t ws_size,
                              hipStream_t stream) {
  const float* x    = (const float*)d_in[0];
  const int*   ei   = (const int*)d_in[1];
  const float* W1   = (const float*)d_in[2];
  const float* as1w = (const float*)d_in[3];
  const float* ad1w = (const float*)d_in[4];
  const float* b1   = (const float*)d_in[5];
  const float* W2   = (const float*)d_in[6];
  const float* as2w = (const float*)d_in[7];
  const float* ad2w = (const float*)d_in[8];
  const float* b2   = (const float*)d_in[9];
  const float* Wc   = (const float*)d_in[10];
  const float* bc   = (const float*)d_in[11];
  float* out = (float*)d_out;

  const int* src = ei;
  const int* dst = ei + NE;

  // ---- workspace layout ----
  char* p = (char*)d_ws;
  float* h1   = (float*)p; p += sizeof(float) * (long long)NN * 128;
  float* out1 = (float*)p; p += sizeof(float) * (long long)NN * 64;
  float* h2   = (float*)p; p += sizeof(float) * (long long)NN * 64;
  float* as1  = (float*)p; p += sizeof(float) * NN * 2;
  float* ad1  = (float*)p; p += sizeof(float) * NN * 2;
  float* as2  = (float*)p; p += sizeof(float) * NN;
  float* ad2  = (float*)p; p += sizeof(float) * NN;
  int* deg     = (int*)p; p += sizeof(int) * NN;
  int* cursor  = (int*)p; p += sizeof(int) * NN;
  int* rowptr  = (int*)p; p += sizeof(int) * (NN + 1);
  int* part    = (int*)p; p += sizeof(int) * ((NSCAN + 63) & ~63);
  int* csr_src = (int*)p; p += sizeof(int) * (long long)NT;

  // ---- CSR build (graph is identical for both layers) ----
  k_csr_zero<<<(NN + 255) / 256, 256, 0, stream>>>(deg, cursor);
  k_csr_count<<<(NT + 255) / 256, 256, 0, stream>>>(dst, deg);
  k_scan1<<<NSCAN, SCAN_BLK, 0, stream>>>(deg, rowptr, part);
  k_scan2<<<1, 64, 0, stream>>>(part);
  k_scan3<<<NSCAN, SCAN_BLK, 0, stream>>>(rowptr, part);
  k_csr_scatter<<<(NT + 255) / 256, 256, 0, stream>>>(src, dst, rowptr, cursor, csr_src);

  // ---- layer 1 ----
  k_gemm1<<<(NN + 7) / 8, 128, 0, stream>>>(x, W1, as1w, ad1w, h1, as1, ad1);
  k_gat1<<<NN, 128, 0, stream>>>(rowptr, csr_src, h1, as1, ad1, b1, out1);

  // ---- layer 2 ----
  k_gemm2<<<(NN + 15) / 16, 64, 0, stream>>>(out1, W2, as2w, ad2w, h2, as2, ad2);
  k_gat2<<<(NN + 3) / 4, 256, 0, stream>>>(rowptr, csr_src, h2, as2, ad2, b2, Wc, bc, out);
}

// Round 3
// 353.559 us; speedup vs baseline: 3.0912x; 1.5704x over previous
//
#include <hip/hip_runtime.h>
#include <math.h>

#define NN 50000          // nodes
#define NE 800000         // edges (without self loops)
#define NT (NE + NN)      // edges incl self loops
#define SCAN_BLK 1024
#define NSCAN ((NN + SCAN_BLK - 1) / SCAN_BLK)   // 49

// ================= CSR build =================
__global__ __launch_bounds__(256) void k_csr_zero(int* deg, int* cursor) {
  int i = blockIdx.x * 256 + threadIdx.x;
  if (i < NN) { deg[i] = 0; cursor[i] = 0; }
}

__global__ __launch_bounds__(256) void k_csr_count(const int* __restrict__ dst, int* __restrict__ deg) {
  int i = blockIdx.x * 256 + threadIdx.x;
  if (i >= NT) return;
  int d = (i < NE) ? dst[i] : (i - NE);
  atomicAdd(&deg[d], 1);
}

__global__ __launch_bounds__(SCAN_BLK) void k_scan1(const int* __restrict__ deg,
                                                    int* __restrict__ rowptr, int* __restrict__ part) {
  __shared__ int s[SCAN_BLK];
  int t = threadIdx.x;
  int g = blockIdx.x * SCAN_BLK + t;
  s[t] = (g < NN) ? deg[g] : 0;
  __syncthreads();
  for (int off = 1; off < SCAN_BLK; off <<= 1) {
    int u = (t >= off) ? s[t - off] : 0;
    __syncthreads();
    s[t] += u;
    __syncthreads();
  }
  if (g < NN) rowptr[g + 1] = s[t];
  if (t == SCAN_BLK - 1) part[blockIdx.x] = s[t];
}

__global__ void k_scan2(int* part) {
  if (threadIdx.x == 0 && blockIdx.x == 0) {
    int run = 0;
    for (int b = 0; b < NSCAN; ++b) { int v = part[b]; part[b] = run; run += v; }
  }
}

__global__ __launch_bounds__(SCAN_BLK) void k_scan3(int* __restrict__ rowptr, const int* __restrict__ part) {
  int t = threadIdx.x;
  int g = blockIdx.x * SCAN_BLK + t;
  if (g < NN) rowptr[g + 1] += part[blockIdx.x];
  if (g == 0) rowptr[0] = 0;
}

__global__ __launch_bounds__(256) void k_csr_scatter(const int* __restrict__ src, const int* __restrict__ dst,
                                                     const int* __restrict__ rowptr, int* __restrict__ cursor,
                                                     int* __restrict__ csr_src) {
  int i = blockIdx.x * 256 + threadIdx.x;
  if (i >= NT) return;
  int s, d;
  if (i < NE) { s = src[i]; d = dst[i]; } else { s = d = i - NE; }
  int pos = atomicAdd(&cursor[d], 1);
  csr_src[rowptr[d] + pos] = s;
}

// ================= layer 1 GEMM: x[50000x128] @ W1[128x128] =================
// 64x128 tile, 128 threads, 8x8 outputs/thread, A transposed in LDS.
// Fused alpha reductions in epilogue.
__global__ __launch_bounds__(128, 2) void k_gemm1(
    const float* __restrict__ x, const float* __restrict__ W1,
    const float* __restrict__ asw_g, const float* __restrict__ adw_g,
    float* __restrict__ h1, float* __restrict__ as1, float* __restrict__ ad1) {
  __shared__ float sA[32][64];     // [k][row]
  __shared__ float sB[32][128];    // [k][col]
  const int t = threadIdx.x;
  const int tc = t & 15;           // 16 col groups x 8 cols
  const int tr = t >> 4;           // 8 row groups x 8 rows
  const int n0 = blockIdx.x * 64;

  float asw_t[8], adw_t[8];
#pragma unroll
  for (int j = 0; j < 8; ++j) { asw_t[j] = asw_g[tc * 8 + j]; adw_t[j] = adw_g[tc * 8 + j]; }

  float acc[8][8];
#pragma unroll
  for (int i = 0; i < 8; ++i)
#pragma unroll
    for (int j = 0; j < 8; ++j) acc[i][j] = 0.f;

  for (int kc = 0; kc < 128; kc += 32) {
    // stage A (transposed): 64 rows x 32 k = 512 float4, 4/thread
#pragma unroll
    for (int f = 0; f < 4; ++f) {
      int id = t * 4 + f;
      int row = id >> 3;           // 8 float4 per row
      int q = id & 7;
      float4 v = make_float4(0.f, 0.f, 0.f, 0.f);
      int n = n0 + row;
      if (n < NN) v = *(const float4*)&x[(long long)n * 128 + kc + q * 4];
      sA[q * 4 + 0][row] = v.x; sA[q * 4 + 1][row] = v.y;
      sA[q * 4 + 2][row] = v.z; sA[q * 4 + 3][row] = v.w;
    }
    // stage B: 32 k x 128 cols = 1024 float4, 8/thread (direct copy)
#pragma unroll
    for (int f = 0; f < 8; ++f) {
      int id = t * 8 + f;
      int kk = id >> 5;
      int c4 = id & 31;
      *(float4*)&sB[kk][c4 * 4] = *(const float4*)&W1[(long long)(kc + kk) * 128 + c4 * 4];
    }
    __syncthreads();
#pragma unroll 4
    for (int kk = 0; kk < 32; ++kk) {
      float a[8], b[8];
      *(float4*)&a[0] = *(const float4*)&sA[kk][tr * 8];
      *(float4*)&a[4] = *(const float4*)&sA[kk][tr * 8 + 4];
      *(float4*)&b[0] = *(const float4*)&sB[kk][tc * 8];
      *(float4*)&b[4] = *(const float4*)&sB[kk][tc * 8 + 4];
#pragma unroll
      for (int i = 0; i < 8; ++i)
#pragma unroll
        for (int j = 0; j < 8; ++j) acc[i][j] += a[i] * b[j];
    }
    __syncthreads();
  }

  const int head = tc >> 3;
#pragma unroll
  for (int i = 0; i < 8; ++i) {
    int n = n0 + tr * 8 + i;
    if (n >= NN) break;
    *(float4*)&h1[(long long)n * 128 + tc * 8] =
        make_float4(acc[i][0], acc[i][1], acc[i][2], acc[i][3]);
    *(float4*)&h1[(long long)n * 128 + tc * 8 + 4] =
        make_float4(acc[i][4], acc[i][5], acc[i][6], acc[i][7]);
    float vs = 0.f, vd = 0.f;
#pragma unroll
    for (int j = 0; j < 8; ++j) { vs += acc[i][j] * asw_t[j]; vd += acc[i][j] * adw_t[j]; }
    vs += __shfl_xor(vs, 1); vd += __shfl_xor(vd, 1);
    vs += __shfl_xor(vs, 2); vd += __shfl_xor(vd, 2);
    vs += __shfl_xor(vs, 4); vd += __shfl_xor(vd, 4);
    if ((tc & 7) == 0) { as1[n * 2 + head] = vs; ad1[n * 2 + head] = vd; }
  }
}

// ================= layer 1 fused GAT: online softmax + aggregate + mean + ELU =================
__global__ __launch_bounds__(128) void k_gat1(
    const int* __restrict__ rowptr, const int* __restrict__ csr_src,
    const float* __restrict__ h1, const float* __restrict__ as1, const float* __restrict__ ad1,
    const float* __restrict__ b1, float* __restrict__ out1) {
  const int n = blockIdx.x;
  const int t = threadIdx.x;
  const int head = t >> 6;
  const int beg = rowptr[n], end = rowptr[n + 1];
  const float ad = ad1[n * 2 + head];
  float m = -1e30f, denom = 0.f, acc = 0.f;
  for (int k = beg; k < end; ++k) {
    int s = csr_src[k];
    float e = as1[s * 2 + head] + ad;
    e = e > 0.f ? e : 0.2f * e;
    if (e > m) {
      float r = __expf(m - e);
      acc *= r; denom *= r; m = e;
    }
    float w = __expf(e - m);
    denom += w;
    acc += w * h1[s * 128 + t];
  }
  float v = acc / (denom + 1e-16f);
  __shared__ float tmp[64];
  if (t >= 64) tmp[t - 64] = v;
  __syncthreads();
  if (t < 64) {
    float u = 0.5f * (v + tmp[t]) + b1[t];
    u = u > 0.f ? u : expm1f(u);
    out1[n * 64 + t] = u;
  }
}

// ================= layer 2 GEMM: out1[50000x64] @ W2[64x64] =================
// 128x64 tile, 128 threads, 8x8/thread. W2 fully staged; A transposed [k][row].
__global__ __launch_bounds__(128, 2) void k_gemm2(
    const float* __restrict__ in, const float* __restrict__ W2,
    const float* __restrict__ asw_g, const float* __restrict__ adw_g,
    float* __restrict__ h2, float* __restrict__ as2, float* __restrict__ ad2) {
  __shared__ float sB[64][64];     // full W2
  __shared__ float sA[32][132];    // [k][row], padded to 132 (16B-aligned rows)
  const int t = threadIdx.x;
  const int tc = t & 7;            // 8 col groups x 8 cols
  const int tr = t >> 3;           // 16 row groups x 8 rows
  const int n0 = blockIdx.x * 128;

  // stage all of W2: 1024 float4, 8/thread
#pragma unroll
  for (int f = 0; f < 8; ++f) {
    int id = t * 8 + f;
    int kk = id >> 4;
    int c4 = id & 15;
    *(float4*)&sB[kk][c4 * 4] = *(const float4*)&W2[kk * 64 + c4 * 4];
  }

  float asw_t[8], adw_t[8];
#pragma unroll
  for (int j = 0; j < 8; ++j) { asw_t[j] = asw_g[tc * 8 + j]; adw_t[j] = adw_g[tc * 8 + j]; }

  float acc[8][8];
#pragma unroll
  for (int i = 0; i < 8; ++i)
#pragma unroll
    for (int j = 0; j < 8; ++j) acc[i][j] = 0.f;

  for (int kc = 0; kc < 64; kc += 32) {
    // stage A transposed: 128 rows x 32 k = 1024 float4, 8/thread
#pragma unroll
    for (int f = 0; f < 8; ++f) {
      int id = f * 128 + t;
      int row = id >> 3;
      int q = id & 7;
      float4 v = make_float4(0.f, 0.f, 0.f, 0.f);
      int n = n0 + row;
      if (n < NN) v = *(const float4*)&in[(long long)n * 64 + kc + q * 4];
      sA[q * 4 + 0][row] = v.x; sA[q * 4 + 1][row] = v.y;
      sA[q * 4 + 2][row] = v.z; sA[q * 4 + 3][row] = v.w;
    }
    __syncthreads();
#pragma unroll 4
    for (int kk = 0; kk < 32; ++kk) {
      float a[8], b[8];
      *(float4*)&a[0] = *(const float4*)&sA[kk][tr * 8];
      *(float4*)&a[4] = *(const float4*)&sA[kk][tr * 8 + 4];
      *(float4*)&b[0] = *(const float4*)&sB[kc + kk][tc * 8];
      *(float4*)&b[4] = *(const float4*)&sB[kc + kk][tc * 8 + 4];
#pragma unroll
      for (int i = 0; i < 8; ++i)
#pragma unroll
        for (int j = 0; j < 8; ++j) acc[i][j] += a[i] * b[j];
    }
    __syncthreads();
  }

#pragma unroll
  for (int i = 0; i < 8; ++i) {
    int n = n0 + tr * 8 + i;
    if (n >= NN) break;
    *(float4*)&h2[(long long)n * 64 + tc * 8] =
        make_float4(acc[i][0], acc[i][1], acc[i][2], acc[i][3]);
    *(float4*)&h2[(long long)n * 64 + tc * 8 + 4] =
        make_float4(acc[i][4], acc[i][5], acc[i][6], acc[i][7]);
    float vs = 0.f, vd = 0.f;
#pragma unroll
    for (int j = 0; j < 8; ++j) { vs += acc[i][j] * asw_t[j]; vd += acc[i][j] * adw_t[j]; }
    vs += __shfl_xor(vs, 1); vd += __shfl_xor(vd, 1);
    vs += __shfl_xor(vs, 2); vd += __shfl_xor(vd, 2);
    vs += __shfl_xor(vs, 4); vd += __shfl_xor(vd, 4);
    if (tc == 0) { as2[n] = vs; ad2[n] = vd; }
  }
}

// ================= layer 2 fused GAT + classifier + log_softmax =================
__global__ __launch_bounds__(256) void k_gat2(
    const int* __restrict__ rowptr, const int* __restrict__ csr_src,
    const float* __restrict__ h2, const float* __restrict__ as2, const float* __restrict__ ad2,
    const float* __restrict__ b2, const float* __restrict__ Wc, const float* __restrict__ bc,
    float* __restrict__ out) {
  const int t = threadIdx.x;
  const int wave = t >> 6;
  const int c = t & 63;
  const int n = blockIdx.x * 4 + wave;
  if (n >= NN) return;
  const int beg = rowptr[n], end = rowptr[n + 1];
  const float ad = ad2[n];
  float m = -1e30f, denom = 0.f, acc = 0.f;
  for (int k = beg; k < end; ++k) {
    int s = csr_src[k];
    float e = as2[s] + ad;
    e = e > 0.f ? e : 0.2f * e;
    if (e > m) {
      float r = __expf(m - e);
      acc *= r; denom *= r; m = e;
    }
    float w = __expf(e - m);
    denom += w;
    acc += w * h2[s * 64 + c];
  }
  float v = acc / (denom + 1e-16f) + b2[c];
  v = v > 0.f ? v : expm1f(v);
  float l0 = v * Wc[c * 2], l1 = v * Wc[c * 2 + 1];
  for (int off = 32; off > 0; off >>= 1) {
    l0 += __shfl_down(l0, off);
    l1 += __shfl_down(l1, off);
  }
  if (c == 0) {
    l0 += bc[0]; l1 += bc[1];
    float mx = fmaxf(l0, l1);
    float lse = mx + logf(expf(l0 - mx) + expf(l1 - mx));
    out[n * 2] = l0 - lse;
    out[n * 2 + 1] = l1 - lse;
  }
}

extern "C" void kernel_launch(void* const* d_in, const int* in_sizes, int n_in,
                              void* d_out, int out_size, void* d_ws, size_t ws_size,
                              hipStream_t stream) {
  const float* x    = (const float*)d_in[0];
  const int*   ei   = (const int*)d_in[1];
  const float* W1   = (const float*)d_in[2];
  const float* as1w = (const float*)d_in[3];
  const float* ad1w = (const float*)d_in[4];
  const float* b1   = (const float*)d_in[5];
  const float* W2   = (const float*)d_in[6];
  const float* as2w = (const float*)d_in[7];
  const float* ad2w = (const float*)d_in[8];
  const float* b2   = (const float*)d_in[9];
  const float* Wc   = (const float*)d_in[10];
  const float* bc   = (const float*)d_in[11];
  float* out = (float*)d_out;

  const int* src = ei;
  const int* dst = ei + NE;

  // ---- workspace layout ----
  char* p = (char*)d_ws;
  float* h1   = (float*)p; p += sizeof(float) * (long long)NN * 128;
  float* out1 = (float*)p; p += sizeof(float) * (long long)NN * 64;
  float* h2   = (float*)p; p += sizeof(float) * (long long)NN * 64;
  float* as1  = (float*)p; p += sizeof(float) * NN * 2;
  float* ad1  = (float*)p; p += sizeof(float) * NN * 2;
  float* as2  = (float*)p; p += sizeof(float) * NN;
  float* ad2  = (float*)p; p += sizeof(float) * NN;
  int* deg     = (int*)p; p += sizeof(int) * NN;
  int* cursor  = (int*)p; p += sizeof(int) * NN;
  int* rowptr  = (int*)p; p += sizeof(int) * (NN + 1);
  int* part    = (int*)p; p += sizeof(int) * ((NSCAN + 63) & ~63);
  int* csr_src = (int*)p; p += sizeof(int) * (long long)NT;

  // ---- CSR build (graph shared by both layers) ----
  k_csr_zero<<<(NN + 255) / 256, 256, 0, stream>>>(deg, cursor);
  k_csr_count<<<(NT + 255) / 256, 256, 0, stream>>>(dst, deg);
  k_scan1<<<NSCAN, SCAN_BLK, 0, stream>>>(deg, rowptr, part);
  k_scan2<<<1, 64, 0, stream>>>(part);
  k_scan3<<<NSCAN, SCAN_BLK, 0, stream>>>(rowptr, part);
  k_csr_scatter<<<(NT + 255) / 256, 256, 0, stream>>>(src, dst, rowptr, cursor, csr_src);

  // ---- layer 1 ----
  k_gemm1<<<(NN + 63) / 64, 128, 0, stream>>>(x, W1, as1w, ad1w, h1, as1, ad1);
  k_gat1<<<NN, 128, 0, stream>>>(rowptr, csr_src, h1, as1, ad1, b1, out1);

  // ---- layer 2 ----
  k_gemm2<<<(NN + 127) / 128, 128, 0, stream>>>(out1, W2, as2w, ad2w, h2, as2, ad2);
  k_gat2<<<(NN + 3) / 4, 256, 0, stream>>>(rowptr, csr_src, h2, as2, ad2, b2, Wc, bc, out);
}

// Round 4
// 303.259 us; speedup vs baseline: 3.6039x; 1.1659x over previous
//
#include <hip/hip_runtime.h>
#include <math.h>

#define NN 50000          // nodes
#define NE 800000         // edges (without self loops)
#define NT (NE + NN)      // edges incl self loops
#define SCAN_BLK 1024
#define NSCAN ((NN + SCAN_BLK - 1) / SCAN_BLK)   // 49

// pack two fp32 -> bf16x2 (RNE); unpack is just shifts
__device__ __forceinline__ unsigned pk_bf16x2(float x, float y) {
  unsigned ux = __float_as_uint(x); ux = ux + 0x7FFFu + ((ux >> 16) & 1u);
  unsigned uy = __float_as_uint(y); uy = uy + 0x7FFFu + ((uy >> 16) & 1u);
  return (ux >> 16) | (uy & 0xFFFF0000u);
}

// ================= CSR build =================
__global__ __launch_bounds__(256) void k_csr_zero(int* deg, int* cursor) {
  int i = blockIdx.x * 256 + threadIdx.x;
  if (i < NN) { deg[i] = 0; cursor[i] = 0; }
}

__global__ __launch_bounds__(256) void k_csr_count(const int* __restrict__ dst, int* __restrict__ deg) {
  int i = blockIdx.x * 256 + threadIdx.x;
  if (i >= NT) return;
  int d = (i < NE) ? dst[i] : (i - NE);
  atomicAdd(&deg[d], 1);
}

__global__ __launch_bounds__(SCAN_BLK) void k_scan1(const int* __restrict__ deg,
                                                    int* __restrict__ rowptr, int* __restrict__ part) {
  __shared__ int s[SCAN_BLK];
  int t = threadIdx.x;
  int g = blockIdx.x * SCAN_BLK + t;
  s[t] = (g < NN) ? deg[g] : 0;
  __syncthreads();
  for (int off = 1; off < SCAN_BLK; off <<= 1) {
    int u = (t >= off) ? s[t - off] : 0;
    __syncthreads();
    s[t] += u;
    __syncthreads();
  }
  if (g < NN) rowptr[g + 1] = s[t];
  if (t == SCAN_BLK - 1) part[blockIdx.x] = s[t];
}

__global__ void k_scan2(int* part) {
  if (threadIdx.x == 0 && blockIdx.x == 0) {
    int run = 0;
    for (int b = 0; b < NSCAN; ++b) { int v = part[b]; part[b] = run; run += v; }
  }
}

__global__ __launch_bounds__(SCAN_BLK) void k_scan3(int* __restrict__ rowptr, const int* __restrict__ part) {
  int t = threadIdx.x;
  int g = blockIdx.x * SCAN_BLK + t;
  if (g < NN) rowptr[g + 1] += part[blockIdx.x];
  if (g == 0) rowptr[0] = 0;
}

__global__ __launch_bounds__(256) void k_csr_scatter(const int* __restrict__ src, const int* __restrict__ dst,
                                                     const int* __restrict__ rowptr, int* __restrict__ cursor,
                                                     int* __restrict__ csr_src) {
  int i = blockIdx.x * 256 + threadIdx.x;
  if (i >= NT) return;
  int s, d;
  if (i < NE) { s = src[i]; d = dst[i]; } else { s = d = i - NE; }
  int pos = atomicAdd(&cursor[d], 1);
  csr_src[rowptr[d] + pos] = s;
}

// ================= layer 1 GEMM: x[50000x128] @ W1[128x128] -> bf16 h1b =================
// 64x128 tile, 128 threads, 8x8 outputs/thread, fused alpha reductions.
__global__ __launch_bounds__(128, 2) void k_gemm1(
    const float* __restrict__ x, const float* __restrict__ W1,
    const float* __restrict__ asw_g, const float* __restrict__ adw_g,
    unsigned* __restrict__ h1u, float* __restrict__ as1, float* __restrict__ ad1) {
  __shared__ float sA[32][64];     // [k][row]
  __shared__ float sB[32][128];    // [k][col]
  const int t = threadIdx.x;
  const int tc = t & 15;           // 16 col groups x 8 cols
  const int tr = t >> 4;           // 8 row groups x 8 rows
  const int n0 = blockIdx.x * 64;

  float asw_t[8], adw_t[8];
#pragma unroll
  for (int j = 0; j < 8; ++j) { asw_t[j] = asw_g[tc * 8 + j]; adw_t[j] = adw_g[tc * 8 + j]; }

  float acc[8][8];
#pragma unroll
  for (int i = 0; i < 8; ++i)
#pragma unroll
    for (int j = 0; j < 8; ++j) acc[i][j] = 0.f;

  for (int kc = 0; kc < 128; kc += 32) {
#pragma unroll
    for (int f = 0; f < 4; ++f) {
      int id = t * 4 + f;
      int row = id >> 3;
      int q = id & 7;
      float4 v = make_float4(0.f, 0.f, 0.f, 0.f);
      int n = n0 + row;
      if (n < NN) v = *(const float4*)&x[(long long)n * 128 + kc + q * 4];
      sA[q * 4 + 0][row] = v.x; sA[q * 4 + 1][row] = v.y;
      sA[q * 4 + 2][row] = v.z; sA[q * 4 + 3][row] = v.w;
    }
#pragma unroll
    for (int f = 0; f < 8; ++f) {
      int id = t * 8 + f;
      int kk = id >> 5;
      int c4 = id & 31;
      *(float4*)&sB[kk][c4 * 4] = *(const float4*)&W1[(long long)(kc + kk) * 128 + c4 * 4];
    }
    __syncthreads();
#pragma unroll 4
    for (int kk = 0; kk < 32; ++kk) {
      float a[8], b[8];
      *(float4*)&a[0] = *(const float4*)&sA[kk][tr * 8];
      *(float4*)&a[4] = *(const float4*)&sA[kk][tr * 8 + 4];
      *(float4*)&b[0] = *(const float4*)&sB[kk][tc * 8];
      *(float4*)&b[4] = *(const float4*)&sB[kk][tc * 8 + 4];
#pragma unroll
      for (int i = 0; i < 8; ++i)
#pragma unroll
        for (int j = 0; j < 8; ++j) acc[i][j] += a[i] * b[j];
    }
    __syncthreads();
  }

  const int head = tc >> 3;
#pragma unroll
  for (int i = 0; i < 8; ++i) {
    int n = n0 + tr * 8 + i;
    if (n >= NN) break;
    uint4 pv;
    pv.x = pk_bf16x2(acc[i][0], acc[i][1]);
    pv.y = pk_bf16x2(acc[i][2], acc[i][3]);
    pv.z = pk_bf16x2(acc[i][4], acc[i][5]);
    pv.w = pk_bf16x2(acc[i][6], acc[i][7]);
    *(uint4*)&h1u[(long long)n * 64 + tc * 4] = pv;
    float vs = 0.f, vd = 0.f;
#pragma unroll
    for (int j = 0; j < 8; ++j) { vs += acc[i][j] * asw_t[j]; vd += acc[i][j] * adw_t[j]; }
    vs += __shfl_xor(vs, 1); vd += __shfl_xor(vd, 1);
    vs += __shfl_xor(vs, 2); vd += __shfl_xor(vd, 2);
    vs += __shfl_xor(vs, 4); vd += __shfl_xor(vd, 4);
    if ((tc & 7) == 0) { as1[n * 2 + head] = vs; ad1[n * 2 + head] = vd; }
  }
}

// ================= layer 1 softmax weights: w=exp(e-max), denom =================
// wave per node; lanes 0-31 -> head 0, lanes 32-63 -> head 1
__global__ __launch_bounds__(256) void k_wts1(
    const int* __restrict__ rowptr, const int* __restrict__ csr_src,
    const float* __restrict__ as1, const float* __restrict__ ad1,
    float* __restrict__ wbuf, float* __restrict__ den1) {
  const int t = threadIdx.x;
  const int n = blockIdx.x * 4 + (t >> 6);
  if (n >= NN) return;
  const int lane = t & 63;
  const int h = lane >> 5;
  const int l = lane & 31;
  const int beg = rowptr[n], end = rowptr[n + 1];
  const float adh = ad1[n * 2 + h];
  float m = -1e30f;
  for (int k = beg + l; k < end; k += 32) {
    float e = as1[csr_src[k] * 2 + h] + adh;
    e = e > 0.f ? e : 0.2f * e;
    m = fmaxf(m, e);
  }
#pragma unroll
  for (int off = 1; off < 32; off <<= 1) m = fmaxf(m, __shfl_xor(m, off));
  float sum = 0.f;
  for (int k = beg + l; k < end; k += 32) {
    float e = as1[csr_src[k] * 2 + h] + adh;
    e = e > 0.f ? e : 0.2f * e;
    float w = __expf(e - m);
    wbuf[2 * k + h] = w;
    sum += w;
  }
#pragma unroll
  for (int off = 1; off < 32; off <<= 1) sum += __shfl_xor(sum, off);
  if (l == 0) den1[n * 2 + h] = sum;
}

// ================= layer 1 aggregation: weighted SpMM over bf16 rows + mean + ELU =================
// wave per node; lane p handles channels (2p, 2p+1); head = p>>5
__global__ __launch_bounds__(256) void k_gat1(
    const int* __restrict__ rowptr, const int* __restrict__ csr_src,
    const unsigned* __restrict__ h1u, const float* __restrict__ wbuf,
    const float* __restrict__ den1, const float* __restrict__ b1,
    float* __restrict__ out1) {
  const int t = threadIdx.x;
  const int n = blockIdx.x * 4 + (t >> 6);
  if (n >= NN) return;
  const int p = t & 63;
  const int beg = rowptr[n], end = rowptr[n + 1];
  float acc0 = 0.f, acc1 = 0.f;
#pragma unroll 2
  for (int k = beg; k < end; ++k) {
    int s = csr_src[k];
    float w = wbuf[2 * k + (p >> 5)];
    unsigned v = h1u[s * 64 + p];
    acc0 += w * __uint_as_float(v << 16);
    acc1 += w * __uint_as_float(v & 0xFFFF0000u);
  }
  float inv = 1.f / (den1[n * 2 + (p >> 5)] + 1e-16f);
  acc0 *= inv; acc1 *= inv;
  acc0 += __shfl_xor(acc0, 32);
  acc1 += __shfl_xor(acc1, 32);
  if (p < 32) {
    float u0 = 0.5f * acc0 + b1[2 * p];
    float u1 = 0.5f * acc1 + b1[2 * p + 1];
    u0 = u0 > 0.f ? u0 : expm1f(u0);
    u1 = u1 > 0.f ? u1 : expm1f(u1);
    *(float2*)&out1[(long long)n * 64 + 2 * p] = make_float2(u0, u1);
  }
}

// ================= layer 2 GEMM: out1[50000x64] @ W2[64x64] -> bf16 h2b =================
__global__ __launch_bounds__(128, 2) void k_gemm2(
    const float* __restrict__ in, const float* __restrict__ W2,
    const float* __restrict__ asw_g, const float* __restrict__ adw_g,
    unsigned* __restrict__ h2u, float* __restrict__ as2, float* __restrict__ ad2) {
  __shared__ float sB[64][64];
  __shared__ float sA[32][132];
  const int t = threadIdx.x;
  const int tc = t & 7;
  const int tr = t >> 3;
  const int n0 = blockIdx.x * 128;

#pragma unroll
  for (int f = 0; f < 8; ++f) {
    int id = t * 8 + f;
    int kk = id >> 4;
    int c4 = id & 15;
    *(float4*)&sB[kk][c4 * 4] = *(const float4*)&W2[kk * 64 + c4 * 4];
  }

  float asw_t[8], adw_t[8];
#pragma unroll
  for (int j = 0; j < 8; ++j) { asw_t[j] = asw_g[tc * 8 + j]; adw_t[j] = adw_g[tc * 8 + j]; }

  float acc[8][8];
#pragma unroll
  for (int i = 0; i < 8; ++i)
#pragma unroll
    for (int j = 0; j < 8; ++j) acc[i][j] = 0.f;

  for (int kc = 0; kc < 64; kc += 32) {
#pragma unroll
    for (int f = 0; f < 8; ++f) {
      int id = f * 128 + t;
      int row = id >> 3;
      int q = id & 7;
      float4 v = make_float4(0.f, 0.f, 0.f, 0.f);
      int n = n0 + row;
      if (n < NN) v = *(const float4*)&in[(long long)n * 64 + kc + q * 4];
      sA[q * 4 + 0][row] = v.x; sA[q * 4 + 1][row] = v.y;
      sA[q * 4 + 2][row] = v.z; sA[q * 4 + 3][row] = v.w;
    }
    __syncthreads();
#pragma unroll 4
    for (int kk = 0; kk < 32; ++kk) {
      float a[8], b[8];
      *(float4*)&a[0] = *(const float4*)&sA[kk][tr * 8];
      *(float4*)&a[4] = *(const float4*)&sA[kk][tr * 8 + 4];
      *(float4*)&b[0] = *(const float4*)&sB[kc + kk][tc * 8];
      *(float4*)&b[4] = *(const float4*)&sB[kc + kk][tc * 8 + 4];
#pragma unroll
      for (int i = 0; i < 8; ++i)
#pragma unroll
        for (int j = 0; j < 8; ++j) acc[i][j] += a[i] * b[j];
    }
    __syncthreads();
  }

#pragma unroll
  for (int i = 0; i < 8; ++i) {
    int n = n0 + tr * 8 + i;
    if (n >= NN) break;
    uint4 pv;
    pv.x = pk_bf16x2(acc[i][0], acc[i][1]);
    pv.y = pk_bf16x2(acc[i][2], acc[i][3]);
    pv.z = pk_bf16x2(acc[i][4], acc[i][5]);
    pv.w = pk_bf16x2(acc[i][6], acc[i][7]);
    *(uint4*)&h2u[(long long)n * 32 + tc * 4] = pv;
    float vs = 0.f, vd = 0.f;
#pragma unroll
    for (int j = 0; j < 8; ++j) { vs += acc[i][j] * asw_t[j]; vd += acc[i][j] * adw_t[j]; }
    vs += __shfl_xor(vs, 1); vd += __shfl_xor(vd, 1);
    vs += __shfl_xor(vs, 2); vd += __shfl_xor(vd, 2);
    vs += __shfl_xor(vs, 4); vd += __shfl_xor(vd, 4);
    if (tc == 0) { as2[n] = vs; ad2[n] = vd; }
  }
}

// ================= layer 2 softmax weights (1 head) =================
__global__ __launch_bounds__(256) void k_wts2(
    const int* __restrict__ rowptr, const int* __restrict__ csr_src,
    const float* __restrict__ as2, const float* __restrict__ ad2,
    float* __restrict__ wbuf, float* __restrict__ den2) {
  const int t = threadIdx.x;
  const int n = blockIdx.x * 4 + (t >> 6);
  if (n >= NN) return;
  const int l = t & 63;
  const int beg = rowptr[n], end = rowptr[n + 1];
  const float adh = ad2[n];
  float m = -1e30f;
  for (int k = beg + l; k < end; k += 64) {
    float e = as2[csr_src[k]] + adh;
    e = e > 0.f ? e : 0.2f * e;
    m = fmaxf(m, e);
  }
#pragma unroll
  for (int off = 1; off < 64; off <<= 1) m = fmaxf(m, __shfl_xor(m, off));
  float sum = 0.f;
  for (int k = beg + l; k < end; k += 64) {
    float e = as2[csr_src[k]] + adh;
    e = e > 0.f ? e : 0.2f * e;
    float w = __expf(e - m);
    wbuf[k] = w;
    sum += w;
  }
#pragma unroll
  for (int off = 1; off < 64; off <<= 1) sum += __shfl_xor(sum, off);
  if (l == 0) den2[n] = sum;
}

// ================= layer 2 aggregation + ELU + classifier + log_softmax =================
// wave per node; half-wave per alternate edge; lane q handles channels (2q, 2q+1)
__global__ __launch_bounds__(256) void k_gat2(
    const int* __restrict__ rowptr, const int* __restrict__ csr_src,
    const unsigned* __restrict__ h2u, const float* __restrict__ wbuf,
    const float* __restrict__ den2, const float* __restrict__ b2,
    const float* __restrict__ Wc, const float* __restrict__ bc,
    float* __restrict__ out) {
  const int t = threadIdx.x;
  const int n = blockIdx.x * 4 + (t >> 6);
  if (n >= NN) return;
  const int p = t & 63;
  const int half = p >> 5;
  const int q = p & 31;
  const int beg = rowptr[n], end = rowptr[n + 1];
  float acc0 = 0.f, acc1 = 0.f;
  for (int k = beg + half; k < end; k += 2) {
    int s = csr_src[k];
    float w = wbuf[k];
    unsigned v = h2u[s * 32 + q];
    acc0 += w * __uint_as_float(v << 16);
    acc1 += w * __uint_as_float(v & 0xFFFF0000u);
  }
  acc0 += __shfl_xor(acc0, 32);
  acc1 += __shfl_xor(acc1, 32);
  float inv = 1.f / (den2[n] + 1e-16f);
  float v0 = acc0 * inv + b2[2 * q];
  float v1 = acc1 * inv + b2[2 * q + 1];
  v0 = v0 > 0.f ? v0 : expm1f(v0);
  v1 = v1 > 0.f ? v1 : expm1f(v1);
  float l0 = v0 * Wc[4 * q] + v1 * Wc[4 * q + 2];
  float l1 = v0 * Wc[4 * q + 1] + v1 * Wc[4 * q + 3];
#pragma unroll
  for (int off = 1; off < 32; off <<= 1) {
    l0 += __shfl_xor(l0, off);
    l1 += __shfl_xor(l1, off);
  }
  if (p == 0) {
    l0 += bc[0]; l1 += bc[1];
    float mx = fmaxf(l0, l1);
    float lse = mx + logf(expf(l0 - mx) + expf(l1 - mx));
    out[n * 2] = l0 - lse;
    out[n * 2 + 1] = l1 - lse;
  }
}

extern "C" void kernel_launch(void* const* d_in, const int* in_sizes, int n_in,
                              void* d_out, int out_size, void* d_ws, size_t ws_size,
                              hipStream_t stream) {
  const float* x    = (const float*)d_in[0];
  const int*   ei   = (const int*)d_in[1];
  const float* W1   = (const float*)d_in[2];
  const float* as1w = (const float*)d_in[3];
  const float* ad1w = (const float*)d_in[4];
  const float* b1   = (const float*)d_in[5];
  const float* W2   = (const float*)d_in[6];
  const float* as2w = (const float*)d_in[7];
  const float* ad2w = (const float*)d_in[8];
  const float* b2   = (const float*)d_in[9];
  const float* Wc   = (const float*)d_in[10];
  const float* bc   = (const float*)d_in[11];
  float* out = (float*)d_out;

  const int* src = ei;
  const int* dst = ei + NE;

  // ---- workspace layout ----
  char* p = (char*)d_ws;
  unsigned* h1u = (unsigned*)p; p += sizeof(unsigned) * (long long)NN * 64;  // bf16x2 h1
  unsigned* h2u = (unsigned*)p; p += sizeof(unsigned) * (long long)NN * 32;  // bf16x2 h2
  float* out1 = (float*)p; p += sizeof(float) * (long long)NN * 64;
  float* as1  = (float*)p; p += sizeof(float) * NN * 2;
  float* ad1  = (float*)p; p += sizeof(float) * NN * 2;
  float* den1 = (float*)p; p += sizeof(float) * NN * 2;
  float* as2  = (float*)p; p += sizeof(float) * NN;
  float* ad2  = (float*)p; p += sizeof(float) * NN;
  float* den2 = (float*)p; p += sizeof(float) * NN;
  int* deg     = (int*)p; p += sizeof(int) * NN;
  int* cursor  = (int*)p; p += sizeof(int) * NN;
  int* rowptr  = (int*)p; p += sizeof(int) * (NN + 1);
  int* part    = (int*)p; p += sizeof(int) * ((NSCAN + 63) & ~63);
  int* csr_src = (int*)p; p += sizeof(int) * (long long)NT;
  float* wbuf  = (float*)p; p += sizeof(float) * (long long)NT * 2;  // layer2 reuses [0:NT)

  // ---- CSR build (graph shared by both layers) ----
  k_csr_zero<<<(NN + 255) / 256, 256, 0, stream>>>(deg, cursor);
  k_csr_count<<<(NT + 255) / 256, 256, 0, stream>>>(dst, deg);
  k_scan1<<<NSCAN, SCAN_BLK, 0, stream>>>(deg, rowptr, part);
  k_scan2<<<1, 64, 0, stream>>>(part);
  k_scan3<<<NSCAN, SCAN_BLK, 0, stream>>>(rowptr, part);
  k_csr_scatter<<<(NT + 255) / 256, 256, 0, stream>>>(src, dst, rowptr, cursor, csr_src);

  // ---- layer 1 ----
  k_gemm1<<<(NN + 63) / 64, 128, 0, stream>>>(x, W1, as1w, ad1w, h1u, as1, ad1);
  k_wts1<<<(NN + 3) / 4, 256, 0, stream>>>(rowptr, csr_src, as1, ad1, wbuf, den1);
  k_gat1<<<(NN + 3) / 4, 256, 0, stream>>>(rowptr, csr_src, h1u, wbuf, den1, b1, out1);

  // ---- layer 2 ----
  k_gemm2<<<(NN + 127) / 128, 128, 0, stream>>>(out1, W2, as2w, ad2w, h2u, as2, ad2);
  k_wts2<<<(NN + 3) / 4, 256, 0, stream>>>(rowptr, csr_src, as2, ad2, wbuf, den2);
  k_gat2<<<(NN + 3) / 4, 256, 0, stream>>>(rowptr, csr_src, h2u, wbuf, den2, b2, Wc, bc, out);
}

// Round 5
// 269.732 us; speedup vs baseline: 4.0519x; 1.1243x over previous
//
#include <hip/hip_runtime.h>
#include <math.h>

#define NN 50000          // nodes
#define NE 800000         // edges (without self loops)
#define NT (NE + NN)      // edges incl self loops
#define SCAN_BLK 1024
#define NSCAN ((NN + SCAN_BLK - 1) / SCAN_BLK)   // 49

// pack two fp32 -> bf16x2 (RNE); unpack is just shifts
__device__ __forceinline__ unsigned pk_bf16x2(float x, float y) {
  unsigned ux = __float_as_uint(x); ux = ux + 0x7FFFu + ((ux >> 16) & 1u);
  unsigned uy = __float_as_uint(y); uy = uy + 0x7FFFu + ((uy >> 16) & 1u);
  return (ux >> 16) | (uy & 0xFFFF0000u);
}

// ================= CSR build =================
__global__ __launch_bounds__(256) void k_csr_zero(int* deg, int* cursor) {
  int i = blockIdx.x * 256 + threadIdx.x;
  if (i < NN) { deg[i] = 0; cursor[i] = 0; }
}

__global__ __launch_bounds__(256) void k_csr_count(const int* __restrict__ dst, int* __restrict__ deg) {
  int i = blockIdx.x * 256 + threadIdx.x;
  if (i >= NT) return;
  int d = (i < NE) ? dst[i] : (i - NE);
  atomicAdd(&deg[d], 1);
}

__global__ __launch_bounds__(SCAN_BLK) void k_scan1(const int* __restrict__ deg,
                                                    int* __restrict__ rowptr, int* __restrict__ part) {
  __shared__ int s[SCAN_BLK];
  int t = threadIdx.x;
  int g = blockIdx.x * SCAN_BLK + t;
  s[t] = (g < NN) ? deg[g] : 0;
  __syncthreads();
  for (int off = 1; off < SCAN_BLK; off <<= 1) {
    int u = (t >= off) ? s[t - off] : 0;
    __syncthreads();
    s[t] += u;
    __syncthreads();
  }
  if (g < NN) rowptr[g + 1] = s[t];
  if (t == SCAN_BLK - 1) part[blockIdx.x] = s[t];
}

// single-wave shfl scan over the 49 partials (was serial 1-thread loop)
__global__ void k_scan2(int* part) {
  int l = threadIdx.x & 63;
  int v = (l < NSCAN) ? part[l] : 0;
#pragma unroll
  for (int off = 1; off < 64; off <<= 1) {
    int u = __shfl_up(v, off);
    if (l >= off) v += u;
  }
  int ex = __shfl_up(v, 1);
  if (l == 0) ex = 0;
  if (l < NSCAN) part[l] = ex;
}

__global__ __launch_bounds__(SCAN_BLK) void k_scan3(int* __restrict__ rowptr, const int* __restrict__ part) {
  int t = threadIdx.x;
  int g = blockIdx.x * SCAN_BLK + t;
  if (g < NN) rowptr[g + 1] += part[blockIdx.x];
  if (g == 0) rowptr[0] = 0;
}

__global__ __launch_bounds__(256) void k_csr_scatter(const int* __restrict__ src, const int* __restrict__ dst,
                                                     const int* __restrict__ rowptr, int* __restrict__ cursor,
                                                     int* __restrict__ csr_src) {
  int i = blockIdx.x * 256 + threadIdx.x;
  if (i >= NT) return;
  int s, d;
  if (i < NE) { s = src[i]; d = dst[i]; } else { s = d = i - NE; }
  int pos = atomicAdd(&cursor[d], 1);
  csr_src[rowptr[d] + pos] = s;
}

// ================= layer 1 GEMM: x[50000x128] @ W1[128x128] -> bf16 h1u =================
__global__ __launch_bounds__(128, 2) void k_gemm1(
    const float* __restrict__ x, const float* __restrict__ W1,
    const float* __restrict__ asw_g, const float* __restrict__ adw_g,
    unsigned* __restrict__ h1u, float* __restrict__ as1, float* __restrict__ ad1) {
  __shared__ float sA[32][64];     // [k][row]
  __shared__ float sB[32][128];    // [k][col]
  const int t = threadIdx.x;
  const int tc = t & 15;           // 16 col groups x 8 cols
  const int tr = t >> 4;           // 8 row groups x 8 rows
  const int n0 = blockIdx.x * 64;

  float asw_t[8], adw_t[8];
#pragma unroll
  for (int j = 0; j < 8; ++j) { asw_t[j] = asw_g[tc * 8 + j]; adw_t[j] = adw_g[tc * 8 + j]; }

  float acc[8][8];
#pragma unroll
  for (int i = 0; i < 8; ++i)
#pragma unroll
    for (int j = 0; j < 8; ++j) acc[i][j] = 0.f;

  for (int kc = 0; kc < 128; kc += 32) {
#pragma unroll
    for (int f = 0; f < 4; ++f) {
      int id = t * 4 + f;
      int row = id >> 3;
      int q = id & 7;
      float4 v = make_float4(0.f, 0.f, 0.f, 0.f);
      int n = n0 + row;
      if (n < NN) v = *(const float4*)&x[(long long)n * 128 + kc + q * 4];
      sA[q * 4 + 0][row] = v.x; sA[q * 4 + 1][row] = v.y;
      sA[q * 4 + 2][row] = v.z; sA[q * 4 + 3][row] = v.w;
    }
#pragma unroll
    for (int f = 0; f < 8; ++f) {
      int id = t * 8 + f;
      int kk = id >> 5;
      int c4 = id & 31;
      *(float4*)&sB[kk][c4 * 4] = *(const float4*)&W1[(long long)(kc + kk) * 128 + c4 * 4];
    }
    __syncthreads();
#pragma unroll 4
    for (int kk = 0; kk < 32; ++kk) {
      float a[8], b[8];
      *(float4*)&a[0] = *(const float4*)&sA[kk][tr * 8];
      *(float4*)&a[4] = *(const float4*)&sA[kk][tr * 8 + 4];
      *(float4*)&b[0] = *(const float4*)&sB[kk][tc * 8];
      *(float4*)&b[4] = *(const float4*)&sB[kk][tc * 8 + 4];
#pragma unroll
      for (int i = 0; i < 8; ++i)
#pragma unroll
        for (int j = 0; j < 8; ++j) acc[i][j] += a[i] * b[j];
    }
    __syncthreads();
  }

  const int head = tc >> 3;
#pragma unroll
  for (int i = 0; i < 8; ++i) {
    int n = n0 + tr * 8 + i;
    if (n >= NN) break;
    uint4 pv;
    pv.x = pk_bf16x2(acc[i][0], acc[i][1]);
    pv.y = pk_bf16x2(acc[i][2], acc[i][3]);
    pv.z = pk_bf16x2(acc[i][4], acc[i][5]);
    pv.w = pk_bf16x2(acc[i][6], acc[i][7]);
    *(uint4*)&h1u[(long long)n * 64 + tc * 4] = pv;
    float vs = 0.f, vd = 0.f;
#pragma unroll
    for (int j = 0; j < 8; ++j) { vs += acc[i][j] * asw_t[j]; vd += acc[i][j] * adw_t[j]; }
    vs += __shfl_xor(vs, 1); vd += __shfl_xor(vd, 1);
    vs += __shfl_xor(vs, 2); vd += __shfl_xor(vd, 2);
    vs += __shfl_xor(vs, 4); vd += __shfl_xor(vd, 4);
    if ((tc & 7) == 0) { as1[n * 2 + head] = vs; ad1[n * 2 + head] = vd; }
  }
}

// ================= layer 1 fused: softmax stats + weighted SpMM + mean + ELU =================
// wave per node (4 nodes/block); lane p owns packed channels (2p,2p+1), head h=p>>5
__global__ __launch_bounds__(256) void k_gat1(
    const int* __restrict__ rowptr, const int* __restrict__ csr_src,
    const unsigned* __restrict__ h1u, const float* __restrict__ as1,
    const float* __restrict__ ad1, const float* __restrict__ b1,
    float* __restrict__ out1) {
  const int t = threadIdx.x;
  const int n = blockIdx.x * 4 + (t >> 6);
  if (n >= NN) return;
  const int p = t & 63;
  const int h = p >> 5;
  const int beg = rowptr[n], end = rowptr[n + 1];
  const float2 adn = ((const float2*)ad1)[n];

  // pass 1: per-lane online (m,d) for BOTH heads over a 64-stride edge slice
  float m0 = -1e30f, d0 = 0.f, m1 = -1e30f, d1 = 0.f;
  for (int k = beg + p; k < end; k += 64) {
    int s = csr_src[k];
    float2 a = ((const float2*)as1)[s];
    float e0 = a.x + adn.x; e0 = e0 > 0.f ? e0 : 0.2f * e0;
    float e1 = a.y + adn.y; e1 = e1 > 0.f ? e1 : 0.2f * e1;
    if (e0 > m0) { d0 *= __expf(m0 - e0); m0 = e0; }
    d0 += __expf(e0 - m0);
    if (e1 > m1) { d1 *= __expf(m1 - e1); m1 = e1; }
    d1 += __expf(e1 - m1);
  }
#pragma unroll
  for (int off = 1; off < 64; off <<= 1) {
    float mo = __shfl_xor(m0, off), dd = __shfl_xor(d0, off);
    float mn = fmaxf(m0, mo);
    d0 = d0 * __expf(m0 - mn) + dd * __expf(mo - mn);
    m0 = mn;
    mo = __shfl_xor(m1, off); dd = __shfl_xor(d1, off);
    mn = fmaxf(m1, mo);
    d1 = d1 * __expf(m1 - mn) + dd * __expf(mo - mn);
    m1 = mn;
  }
  const float mh  = h ? m1 : m0;
  const float adh = h ? adn.y : adn.x;
  const float inv = 1.f / ((h ? d1 : d0) + 1e-16f);

  // pass 2: 4-edge batched weighted aggregation (4 gather chains in flight)
  float acc0 = 0.f, acc1 = 0.f;
  int k = beg;
  for (; k + 4 <= end; k += 4) {
    int s0 = csr_src[k], s1 = csr_src[k + 1], s2 = csr_src[k + 2], s3 = csr_src[k + 3];
    unsigned v0 = h1u[s0 * 64 + p], v1 = h1u[s1 * 64 + p],
             v2 = h1u[s2 * 64 + p], v3 = h1u[s3 * 64 + p];
    float2 a0 = ((const float2*)as1)[s0], a1 = ((const float2*)as1)[s1],
           a2 = ((const float2*)as1)[s2], a3 = ((const float2*)as1)[s3];
    float e0 = (h ? a0.y : a0.x) + adh; e0 = e0 > 0.f ? e0 : 0.2f * e0;
    float e1 = (h ? a1.y : a1.x) + adh; e1 = e1 > 0.f ? e1 : 0.2f * e1;
    float e2 = (h ? a2.y : a2.x) + adh; e2 = e2 > 0.f ? e2 : 0.2f * e2;
    float e3 = (h ? a3.y : a3.x) + adh; e3 = e3 > 0.f ? e3 : 0.2f * e3;
    float w0 = __expf(e0 - mh), w1 = __expf(e1 - mh),
          w2 = __expf(e2 - mh), w3 = __expf(e3 - mh);
    acc0 += w0 * __uint_as_float(v0 << 16); acc1 += w0 * __uint_as_float(v0 & 0xFFFF0000u);
    acc0 += w1 * __uint_as_float(v1 << 16); acc1 += w1 * __uint_as_float(v1 & 0xFFFF0000u);
    acc0 += w2 * __uint_as_float(v2 << 16); acc1 += w2 * __uint_as_float(v2 & 0xFFFF0000u);
    acc0 += w3 * __uint_as_float(v3 << 16); acc1 += w3 * __uint_as_float(v3 & 0xFFFF0000u);
  }
  for (; k < end; ++k) {
    int s = csr_src[k];
    unsigned v = h1u[s * 64 + p];
    float2 a = ((const float2*)as1)[s];
    float e = (h ? a.y : a.x) + adh; e = e > 0.f ? e : 0.2f * e;
    float w = __expf(e - mh);
    acc0 += w * __uint_as_float(v << 16); acc1 += w * __uint_as_float(v & 0xFFFF0000u);
  }
  acc0 *= inv; acc1 *= inv;
  acc0 += __shfl_xor(acc0, 32);
  acc1 += __shfl_xor(acc1, 32);
  if (p < 32) {
    float u0 = 0.5f * acc0 + b1[2 * p];
    float u1 = 0.5f * acc1 + b1[2 * p + 1];
    u0 = u0 > 0.f ? u0 : expm1f(u0);
    u1 = u1 > 0.f ? u1 : expm1f(u1);
    *(float2*)&out1[(long long)n * 64 + 2 * p] = make_float2(u0, u1);
  }
}

// ================= layer 2 GEMM: out1[50000x64] @ W2[64x64] -> bf16 h2u =================
__global__ __launch_bounds__(128, 2) void k_gemm2(
    const float* __restrict__ in, const float* __restrict__ W2,
    const float* __restrict__ asw_g, const float* __restrict__ adw_g,
    unsigned* __restrict__ h2u, float* __restrict__ as2, float* __restrict__ ad2) {
  __shared__ float sB[64][64];
  __shared__ float sA[32][132];
  const int t = threadIdx.x;
  const int tc = t & 7;
  const int tr = t >> 3;
  const int n0 = blockIdx.x * 128;

#pragma unroll
  for (int f = 0; f < 8; ++f) {
    int id = t * 8 + f;
    int kk = id >> 4;
    int c4 = id & 15;
    *(float4*)&sB[kk][c4 * 4] = *(const float4*)&W2[kk * 64 + c4 * 4];
  }

  float asw_t[8], adw_t[8];
#pragma unroll
  for (int j = 0; j < 8; ++j) { asw_t[j] = asw_g[tc * 8 + j]; adw_t[j] = adw_g[tc * 8 + j]; }

  float acc[8][8];
#pragma unroll
  for (int i = 0; i < 8; ++i)
#pragma unroll
    for (int j = 0; j < 8; ++j) acc[i][j] = 0.f;

  for (int kc = 0; kc < 64; kc += 32) {
#pragma unroll
    for (int f = 0; f < 8; ++f) {
      int id = f * 128 + t;
      int row = id >> 3;
      int q = id & 7;
      float4 v = make_float4(0.f, 0.f, 0.f, 0.f);
      int n = n0 + row;
      if (n < NN) v = *(const float4*)&in[(long long)n * 64 + kc + q * 4];
      sA[q * 4 + 0][row] = v.x; sA[q * 4 + 1][row] = v.y;
      sA[q * 4 + 2][row] = v.z; sA[q * 4 + 3][row] = v.w;
    }
    __syncthreads();
#pragma unroll 4
    for (int kk = 0; kk < 32; ++kk) {
      float a[8], b[8];
      *(float4*)&a[0] = *(const float4*)&sA[kk][tr * 8];
      *(float4*)&a[4] = *(const float4*)&sA[kk][tr * 8 + 4];
      *(float4*)&b[0] = *(const float4*)&sB[kc + kk][tc * 8];
      *(float4*)&b[4] = *(const float4*)&sB[kc + kk][tc * 8 + 4];
#pragma unroll
      for (int i = 0; i < 8; ++i)
#pragma unroll
        for (int j = 0; j < 8; ++j) acc[i][j] += a[i] * b[j];
    }
    __syncthreads();
  }

#pragma unroll
  for (int i = 0; i < 8; ++i) {
    int n = n0 + tr * 8 + i;
    if (n >= NN) break;
    uint4 pv;
    pv.x = pk_bf16x2(acc[i][0], acc[i][1]);
    pv.y = pk_bf16x2(acc[i][2], acc[i][3]);
    pv.z = pk_bf16x2(acc[i][4], acc[i][5]);
    pv.w = pk_bf16x2(acc[i][6], acc[i][7]);
    *(uint4*)&h2u[(long long)n * 32 + tc * 4] = pv;
    float vs = 0.f, vd = 0.f;
#pragma unroll
    for (int j = 0; j < 8; ++j) { vs += acc[i][j] * asw_t[j]; vd += acc[i][j] * adw_t[j]; }
    vs += __shfl_xor(vs, 1); vd += __shfl_xor(vd, 1);
    vs += __shfl_xor(vs, 2); vd += __shfl_xor(vd, 2);
    vs += __shfl_xor(vs, 4); vd += __shfl_xor(vd, 4);
    if (tc == 0) { as2[n] = vs; ad2[n] = vd; }
  }
}

// ================= layer 2 fused: stats + SpMM + ELU + classifier + log_softmax =================
// wave per node; half-waves take alternate edges; lane q owns packed channels (2q,2q+1)
__global__ __launch_bounds__(256) void k_gat2(
    const int* __restrict__ rowptr, const int* __restrict__ csr_src,
    const unsigned* __restrict__ h2u, const float* __restrict__ as2,
    const float* __restrict__ ad2, const float* __restrict__ b2,
    const float* __restrict__ Wc, const float* __restrict__ bc,
    float* __restrict__ out) {
  const int t = threadIdx.x;
  const int n = blockIdx.x * 4 + (t >> 6);
  if (n >= NN) return;
  const int p = t & 63;
  const int half = p >> 5;
  const int q = p & 31;
  const int beg = rowptr[n], end = rowptr[n + 1];
  const float adn = ad2[n];

  // pass 1: per-lane online (m,d), 64-stride
  float m = -1e30f, d = 0.f;
  for (int k = beg + p; k < end; k += 64) {
    float e = as2[csr_src[k]] + adn;
    e = e > 0.f ? e : 0.2f * e;
    if (e > m) { d *= __expf(m - e); m = e; }
    d += __expf(e - m);
  }
#pragma unroll
  for (int off = 1; off < 64; off <<= 1) {
    float mo = __shfl_xor(m, off), dd = __shfl_xor(d, off);
    float mn = fmaxf(m, mo);
    d = d * __expf(m - mn) + dd * __expf(mo - mn);
    m = mn;
  }
  const float inv = 1.f / (d + 1e-16f);

  // pass 2: half-wave alternate edges, 2-edge batches
  float acc0 = 0.f, acc1 = 0.f;
  int k = beg + half;
  for (; k + 2 < end; k += 4) {
    int s0 = csr_src[k], s1 = csr_src[k + 2];
    unsigned v0 = h2u[s0 * 32 + q], v1 = h2u[s1 * 32 + q];
    float e0 = as2[s0] + adn; e0 = e0 > 0.f ? e0 : 0.2f * e0;
    float e1 = as2[s1] + adn; e1 = e1 > 0.f ? e1 : 0.2f * e1;
    float w0 = __expf(e0 - m), w1 = __expf(e1 - m);
    acc0 += w0 * __uint_as_float(v0 << 16); acc1 += w0 * __uint_as_float(v0 & 0xFFFF0000u);
    acc0 += w1 * __uint_as_float(v1 << 16); acc1 += w1 * __uint_as_float(v1 & 0xFFFF0000u);
  }
  if (k < end) {
    int s = csr_src[k];
    unsigned v = h2u[s * 32 + q];
    float e = as2[s] + adn; e = e > 0.f ? e : 0.2f * e;
    float w = __expf(e - m);
    acc0 += w * __uint_as_float(v << 16); acc1 += w * __uint_as_float(v & 0xFFFF0000u);
  }
  acc0 += __shfl_xor(acc0, 32);
  acc1 += __shfl_xor(acc1, 32);
  float v0 = acc0 * inv + b2[2 * q];
  float v1 = acc1 * inv + b2[2 * q + 1];
  v0 = v0 > 0.f ? v0 : expm1f(v0);
  v1 = v1 > 0.f ? v1 : expm1f(v1);
  float l0 = v0 * Wc[4 * q] + v1 * Wc[4 * q + 2];
  float l1 = v0 * Wc[4 * q + 1] + v1 * Wc[4 * q + 3];
#pragma unroll
  for (int off = 1; off < 32; off <<= 1) {
    l0 += __shfl_xor(l0, off);
    l1 += __shfl_xor(l1, off);
  }
  if (p == 0) {
    l0 += bc[0]; l1 += bc[1];
    float mx = fmaxf(l0, l1);
    float lse = mx + logf(expf(l0 - mx) + expf(l1 - mx));
    out[n * 2] = l0 - lse;
    out[n * 2 + 1] = l1 - lse;
  }
}

extern "C" void kernel_launch(void* const* d_in, const int* in_sizes, int n_in,
                              void* d_out, int out_size, void* d_ws, size_t ws_size,
                              hipStream_t stream) {
  const float* x    = (const float*)d_in[0];
  const int*   ei   = (const int*)d_in[1];
  const float* W1   = (const float*)d_in[2];
  const float* as1w = (const float*)d_in[3];
  const float* ad1w = (const float*)d_in[4];
  const float* b1   = (const float*)d_in[5];
  const float* W2   = (const float*)d_in[6];
  const float* as2w = (const float*)d_in[7];
  const float* ad2w = (const float*)d_in[8];
  const float* b2   = (const float*)d_in[9];
  const float* Wc   = (const float*)d_in[10];
  const float* bc   = (const float*)d_in[11];
  float* out = (float*)d_out;

  const int* src = ei;
  const int* dst = ei + NE;

  // ---- workspace layout ----
  char* p = (char*)d_ws;
  unsigned* h1u = (unsigned*)p; p += sizeof(unsigned) * (long long)NN * 64;  // bf16x2 h1
  unsigned* h2u = (unsigned*)p; p += sizeof(unsigned) * (long long)NN * 32;  // bf16x2 h2
  float* out1 = (float*)p; p += sizeof(float) * (long long)NN * 64;
  float* as1  = (float*)p; p += sizeof(float) * NN * 2;
  float* ad1  = (float*)p; p += sizeof(float) * NN * 2;
  float* as2  = (float*)p; p += sizeof(float) * NN;
  float* ad2  = (float*)p; p += sizeof(float) * NN;
  int* deg     = (int*)p; p += sizeof(int) * NN;
  int* cursor  = (int*)p; p += sizeof(int) * NN;
  int* rowptr  = (int*)p; p += sizeof(int) * (NN + 1);
  int* part    = (int*)p; p += sizeof(int) * ((NSCAN + 63) & ~63);
  int* csr_src = (int*)p; p += sizeof(int) * (long long)NT;

  // ---- CSR build (graph shared by both layers) ----
  k_csr_zero<<<(NN + 255) / 256, 256, 0, stream>>>(deg, cursor);
  k_csr_count<<<(NT + 255) / 256, 256, 0, stream>>>(dst, deg);
  k_scan1<<<NSCAN, SCAN_BLK, 0, stream>>>(deg, rowptr, part);
  k_scan2<<<1, 64, 0, stream>>>(part);
  k_scan3<<<NSCAN, SCAN_BLK, 0, stream>>>(rowptr, part);
  k_csr_scatter<<<(NT + 255) / 256, 256, 0, stream>>>(src, dst, rowptr, cursor, csr_src);

  // ---- layer 1 ----
  k_gemm1<<<(NN + 63) / 64, 128, 0, stream>>>(x, W1, as1w, ad1w, h1u, as1, ad1);
  k_gat1<<<(NN + 3) / 4, 256, 0, stream>>>(rowptr, csr_src, h1u, as1, ad1, b1, out1);

  // ---- layer 2 ----
  k_gemm2<<<(NN + 127) / 128, 128, 0, stream>>>(out1, W2, as2w, ad2w, h2u, as2, ad2);
  k_gat2<<<(NN + 3) / 4, 256, 0, stream>>>(rowptr, csr_src, h2u, as2, ad2, b2, Wc, bc, out);
}